// Round 3
// baseline (163.636 us; speedup 1.0000x reference)
//
#include <hip/hip_runtime.h>
#include <hip/hip_bf16.h>
#include <stdint.h>

// SimpleRNN fused kernel: B=16384, T=28, I=28, H=128, C=10, all fp32 I/O.
// One wave per 16 batch rows; whole recurrence in registers via bf16 hi/lo
// split MFMAs; hidden-unit permutation makes D-layout == next B-frag layout.

typedef __attribute__((ext_vector_type(8))) short short8;
typedef __attribute__((ext_vector_type(4))) float f32x4;

union Frag { short8 s; uint32_t u[4]; };

#define MFMA16(a,b,c) __builtin_amdgcn_mfma_f32_16x16x32_bf16((a),(b),(c),0,0,0)

__device__ __forceinline__ uint32_t pk2(float a, float b){
    union { __hip_bfloat162 h; uint32_t u; } cv;
    cv.h = __float22bfloat162_rn(make_float2(a,b));
    return cv.u;
}
__device__ __forceinline__ float lo16f(uint32_t u){ return __builtin_bit_cast(float, u<<16); }
__device__ __forceinline__ float hi16f(uint32_t u){ return __builtin_bit_cast(float, u & 0xffff0000u); }

// 8 fp32 -> bf16 hi frag + bf16 lo (residual) frag
__device__ __forceinline__ void cvt8(const f32x4& a, const f32x4& b, Frag& hi, Frag& lo){
    float v[8];
    #pragma unroll
    for(int i=0;i<4;i++){ v[i]=a[i]; v[4+i]=b[i]; }
    #pragma unroll
    for(int q=0;q<4;q++){
        uint32_t h = pk2(v[2*q], v[2*q+1]);
        hi.u[q] = h;
        lo.u[q] = pk2(v[2*q]-lo16f(h), v[2*q+1]-hi16f(h));
    }
}

// hidden-unit permutation: D slot (jt, rowidx) -> physical hidden index
// rho(jt,rowidx) = 32*(jt>>1) + 8*(rowidx>>2) + 4*(jt&1) + (rowidx&3)
__device__ __forceinline__ int piperm(int p){
    int jt = p>>4, c = p&15;
    return 32*(jt>>1) + 8*(c>>2) + 4*(jt&1) + (c&3);
}

__device__ __forceinline__ float fast_tanh(float x){
    x = fminf(fmaxf(x, -30.f), 30.f);
    float e = __expf(2.f*x);
    return (e-1.f)*__builtin_amdgcn_rcpf(e+1.f);
}

__global__ __launch_bounds__(64,1) void rnn_fused(
    const float* __restrict__ x,   const float* __restrict__ Wih,
    const float* __restrict__ Whh, const float* __restrict__ bih,
    const float* __restrict__ bhh, const float* __restrict__ Wfc,
    const float* __restrict__ bfc, float* __restrict__ out)
{
    const int lane = threadIdx.x & 63;
    const int g = lane>>4, c = lane&15;
    const int b0 = blockIdx.x*16;
    const f32x4 zero4 = {0.f,0.f,0.f,0.f};

    // ---- prologue: W_hh fragments (rows pi-permuted), hi+lo split ----
    Frag whh_h[8][4], whh_l[8][4];
    #pragma unroll
    for(int jt=0;jt<8;jt++){
        const int row = piperm(16*jt + c);
        const float* rp = Whh + row*128;
        #pragma unroll
        for(int kt=0;kt<4;kt++){
            f32x4 a = *(const f32x4*)(rp + kt*32 + 8*g);
            f32x4 b = *(const f32x4*)(rp + kt*32 + 8*g + 4);
            cvt8(a, b, whh_h[jt][kt], whh_l[jt][kt]);
        }
    }

    // ---- W_ih fragments (K=28 padded to 32 with zeros) ----
    Frag wih_h[8], wih_l[8];
    {
        const int i1 = 8*g;
        const int i2 = (g<3) ? (8*g+4) : 24;   // clamped (masked below)
        #pragma unroll
        for(int jt=0;jt<8;jt++){
            const int row = piperm(16*jt + c);
            const float* rp = Wih + row*28;
            f32x4 a = *(const f32x4*)(rp + i1);
            f32x4 b = *(const f32x4*)(rp + i2);
            if (g==3) b = zero4;
            cvt8(a, b, wih_h[jt], wih_l[jt]);
        }
    }

    // ---- biases as MFMA C-operand (pi-permuted) ----
    f32x4 biasr[8];
    #pragma unroll
    for(int jt=0;jt<8;jt++){
        #pragma unroll
        for(int r=0;r<4;r++){
            int q = piperm(16*jt + 4*g + r);
            biasr[jt][r] = bih[q] + bhh[q];
        }
    }

    // ---- h state fragments (B-layout), zero init ----
    Frag bh_h[4], bh_l[4];
    #pragma unroll
    for(int kt=0;kt<4;kt++){
        #pragma unroll
        for(int q=0;q<4;q++){ bh_h[kt].u[q]=0; bh_l[kt].u[q]=0; }
    }

    const float* xrow = x + (size_t)(b0 + c)*784;
    const int o1 = 8*g;
    const int o2 = (g<3) ? (8*g+4) : 24;

    f32x4 xA = *(const f32x4*)(xrow + o1);
    f32x4 xB = *(const f32x4*)(xrow + o2);

    for(int t=0; t<28; ++t){
        // prefetch next timestep's x
        f32x4 xA_n = xA, xB_n = xB;
        if (t < 27){
            xA_n = *(const f32x4*)(xrow + (t+1)*28 + o1);
            xB_n = *(const f32x4*)(xrow + (t+1)*28 + o2);
        }
        // x -> B fragment (zero-pad i>=28)
        Frag bx_h, bx_l;
        {
            f32x4 b = xB;
            if (g==3) b = zero4;
            cvt8(xA, b, bx_h, bx_l);
        }
        // preact = b_ih+b_hh + W_ih x_t + W_hh h   (3-term bf16 split each)
        f32x4 acc[8];
        #pragma unroll
        for(int jt=0;jt<8;jt++){
            acc[jt] = MFMA16(wih_h[jt].s, bx_h.s, biasr[jt]);
            acc[jt] = MFMA16(wih_l[jt].s, bx_h.s, acc[jt]);
            acc[jt] = MFMA16(wih_h[jt].s, bx_l.s, acc[jt]);
            #pragma unroll
            for(int kt=0;kt<4;kt++){
                acc[jt] = MFMA16(whh_h[jt][kt].s, bh_h[kt].s, acc[jt]);
                acc[jt] = MFMA16(whh_l[jt][kt].s, bh_h[kt].s, acc[jt]);
                acc[jt] = MFMA16(whh_h[jt][kt].s, bh_l[kt].s, acc[jt]);
            }
        }
        // tanh + hi/lo pack; D slots rename directly into next B-frags
        Frag nh_h[4], nh_l[4];
        #pragma unroll
        for(int jt=0;jt<8;jt++){
            float h0 = fast_tanh(acc[jt][0]);
            float h1 = fast_tanh(acc[jt][1]);
            float h2 = fast_tanh(acc[jt][2]);
            float h3 = fast_tanh(acc[jt][3]);
            const int kt = jt>>1, q0 = (jt&1)*2;
            uint32_t u0 = pk2(h0,h1), u1 = pk2(h2,h3);
            nh_h[kt].u[q0]   = u0;
            nh_h[kt].u[q0+1] = u1;
            nh_l[kt].u[q0]   = pk2(h0-lo16f(u0), h1-hi16f(u0));
            nh_l[kt].u[q0+1] = pk2(h2-lo16f(u1), h3-hi16f(u1));
        }
        #pragma unroll
        for(int kt=0;kt<4;kt++){ bh_h[kt]=nh_h[kt]; bh_l[kt]=nh_l[kt]; }
        xA = xA_n; xB = xB_n;
    }

    // ---- FC epilogue: logits = W_fc h + b_fc ----
    Frag wfc_h[4], wfc_l[4];
    {
        const bool valid = (c < 10);
        const float* rp = Wfc + (valid ? c : 0)*128;
        #pragma unroll
        for(int kt=0;kt<4;kt++){
            f32x4 a = *(const f32x4*)(rp + kt*32 + 8*g);
            f32x4 b = *(const f32x4*)(rp + kt*32 + 8*g + 4);
            if(!valid){ a = zero4; b = zero4; }
            cvt8(a, b, wfc_h[kt], wfc_l[kt]);
        }
    }
    f32x4 accf = {0.f,0.f,0.f,0.f};
    #pragma unroll
    for(int kt=0;kt<4;kt++){
        accf = MFMA16(wfc_h[kt].s, bh_h[kt].s, accf);
        accf = MFMA16(wfc_l[kt].s, bh_h[kt].s, accf);
        accf = MFMA16(wfc_h[kt].s, bh_l[kt].s, accf);
    }
    #pragma unroll
    for(int r=0;r<4;r++){
        int cls = 4*g + r;
        if (cls < 10){
            out[(size_t)(b0+c)*10 + cls] = accf[r] + bfc[cls];
        }
    }
}

extern "C" void kernel_launch(void* const* d_in, const int* in_sizes, int n_in,
                              void* d_out, int out_size, void* d_ws, size_t ws_size,
                              hipStream_t stream)
{
    const float* x   = (const float*)d_in[0];
    const float* Wih = (const float*)d_in[1];
    const float* Whh = (const float*)d_in[2];
    const float* bih = (const float*)d_in[3];
    const float* bhh = (const float*)d_in[4];
    const float* Wfc = (const float*)d_in[5];
    const float* bfc = (const float*)d_in[6];
    float* out = (float*)d_out;

    const int nb = in_sizes[0] / 784;      // 16384
    dim3 grid(nb/16), blk(64);
    hipLaunchKernelGGL(rnn_fused, grid, blk, 0, stream,
                       x, Wih, Whh, bih, bhh, Wfc, bfc, out);
}

// Round 4
// 148.563 us; speedup vs baseline: 1.1015x; 1.1015x over previous
//
#include <hip/hip_runtime.h>
#include <hip/hip_bf16.h>
#include <stdint.h>

// SimpleRNN fused kernel v2: B=16384, T=28, I=28, H=128, C=10, fp32 I/O.
// 4 waves/block; each wave owns 2 of 8 hidden-row tiles (jt). h exchanged
// per step via double-buffered LDS. bf16 hi/lo split MFMAs, fp32 accum.
// Hidden-unit permutation makes D-layout == next-step B-frag layout.

typedef __attribute__((ext_vector_type(8))) short short8;
typedef __attribute__((ext_vector_type(4))) float f32x4;
typedef __attribute__((ext_vector_type(4))) uint32_t u32x4;

union Frag { short8 s; uint32_t u[4]; u32x4 v; };

#define MFMA16(a,b,c) __builtin_amdgcn_mfma_f32_16x16x32_bf16((a),(b),(c),0,0,0)

__device__ __forceinline__ uint32_t pk2(float a, float b){
    union { __hip_bfloat162 h; uint32_t u; } cv;
    cv.h = __float22bfloat162_rn(make_float2(a,b));
    return cv.u;
}
__device__ __forceinline__ float lo16f(uint32_t u){ return __builtin_bit_cast(float, u<<16); }
__device__ __forceinline__ float hi16f(uint32_t u){ return __builtin_bit_cast(float, u & 0xffff0000u); }

__device__ __forceinline__ void cvt8(const f32x4& a, const f32x4& b, Frag& hi, Frag& lo){
    float v[8];
    #pragma unroll
    for(int i=0;i<4;i++){ v[i]=a[i]; v[4+i]=b[i]; }
    #pragma unroll
    for(int q=0;q<4;q++){
        uint32_t h = pk2(v[2*q], v[2*q+1]);
        hi.u[q] = h;
        lo.u[q] = pk2(v[2*q]-lo16f(h), v[2*q+1]-hi16f(h));
    }
}

// D slot (jt, rowidx) -> physical hidden index (layout fixed point)
__device__ __forceinline__ int piperm(int p){
    int jt = p>>4, c = p&15;
    return 32*(jt>>1) + 8*(c>>2) + 4*(jt&1) + (c&3);
}

__device__ __forceinline__ float fast_tanh(float x){
    x = fminf(fmaxf(x, -30.f), 30.f);
    float e = __expf(2.f*x);
    return (e-1.f)*__builtin_amdgcn_rcpf(e+1.f);
}

__global__ __launch_bounds__(256,2) void rnn_fused4(
    const float* __restrict__ x,   const float* __restrict__ Wih,
    const float* __restrict__ Whh, const float* __restrict__ bih,
    const float* __restrict__ bhh, const float* __restrict__ Wfc,
    const float* __restrict__ bfc, float* __restrict__ out)
{
    const int tid  = threadIdx.x;
    const int w    = tid >> 6;        // wave 0..3, owns jt = 2w, 2w+1 (kt = w)
    const int lane = tid & 63;
    const int g = lane>>4, c = lane&15;
    const int b0 = blockIdx.x*16;
    const f32x4 zero4 = {0.f,0.f,0.f,0.f};

    // double-buffered h exchange: [buf][hi/lo][kt][lane][4 u32] = 16 KB
    __shared__ uint32_t lds[2][2][4][64][4];

    // ---- W_hh fragments for this wave's 2 jt tiles (rows pi-permuted) ----
    Frag whh_h[2][4], whh_l[2][4];
    #pragma unroll
    for(int j=0;j<2;j++){
        const int row = piperm(16*(2*w+j) + c);
        const float* rp = Whh + row*128;
        #pragma unroll
        for(int kt=0;kt<4;kt++){
            f32x4 a = *(const f32x4*)(rp + kt*32 + 8*g);
            f32x4 b = *(const f32x4*)(rp + kt*32 + 8*g + 4);
            cvt8(a, b, whh_h[j][kt], whh_l[j][kt]);
        }
    }

    // ---- W_ih fragments (K=28 padded to 32) ----
    Frag wih_h[2], wih_l[2];
    {
        const int i1 = 8*g;
        const int i2 = (g<3) ? (8*g+4) : 24;
        #pragma unroll
        for(int j=0;j<2;j++){
            const int row = piperm(16*(2*w+j) + c);
            const float* rp = Wih + row*28;
            f32x4 a = *(const f32x4*)(rp + i1);
            f32x4 b = *(const f32x4*)(rp + i2);
            if (g==3) b = zero4;
            cvt8(a, b, wih_h[j], wih_l[j]);
        }
    }

    // ---- biases as MFMA C-operand ----
    f32x4 biasr[2];
    #pragma unroll
    for(int j=0;j<2;j++){
        #pragma unroll
        for(int r=0;r<4;r++){
            int q = piperm(16*(2*w+j) + 4*g + r);
            biasr[j][r] = bih[q] + bhh[q];
        }
    }

    // ---- h state fragments (full 128-wide B-layout), zero init ----
    Frag bh_h[4], bh_l[4];
    #pragma unroll
    for(int kt=0;kt<4;kt++){
        #pragma unroll
        for(int q=0;q<4;q++){ bh_h[kt].u[q]=0; bh_l[kt].u[q]=0; }
    }

    const float* xrow = x + (size_t)(b0 + c)*784;
    const int o1 = 8*g;
    const int o2 = (g<3) ? (8*g+4) : 24;

    f32x4 xA = *(const f32x4*)(xrow + o1);
    f32x4 xB = *(const f32x4*)(xrow + o2);

    for(int t=0; t<28; ++t){
        // prefetch next timestep's x
        f32x4 xA_n = xA, xB_n = xB;
        if (t < 27){
            xA_n = *(const f32x4*)(xrow + (t+1)*28 + o1);
            xB_n = *(const f32x4*)(xrow + (t+1)*28 + o2);
        }
        // x -> B fragment (zero-pad i>=28)
        Frag bx_h, bx_l;
        {
            f32x4 b = xB;
            if (g==3) b = zero4;
            cvt8(xA, b, bx_h, bx_l);
        }
        // preact = bias + W_ih x_t + W_hh h, two independent chains per jt
        f32x4 acc[2];
        #pragma unroll
        for(int j=0;j<2;j++){
            f32x4 a1 = MFMA16(wih_h[j].s, bx_h.s, biasr[j]);
            a1 = MFMA16(wih_l[j].s, bx_h.s, a1);
            a1 = MFMA16(wih_h[j].s, bx_l.s, a1);
            a1 = MFMA16(whh_h[j][0].s, bh_h[0].s, a1);
            a1 = MFMA16(whh_l[j][0].s, bh_h[0].s, a1);
            a1 = MFMA16(whh_h[j][0].s, bh_l[0].s, a1);
            a1 = MFMA16(whh_h[j][1].s, bh_h[1].s, a1);
            a1 = MFMA16(whh_l[j][1].s, bh_h[1].s, a1);
            a1 = MFMA16(whh_h[j][1].s, bh_l[1].s, a1);
            f32x4 a2 = MFMA16(whh_h[j][2].s, bh_h[2].s, zero4);
            a2 = MFMA16(whh_l[j][2].s, bh_h[2].s, a2);
            a2 = MFMA16(whh_h[j][2].s, bh_l[2].s, a2);
            a2 = MFMA16(whh_h[j][3].s, bh_h[3].s, a2);
            a2 = MFMA16(whh_l[j][3].s, bh_h[3].s, a2);
            a2 = MFMA16(whh_h[j][3].s, bh_l[3].s, a2);
            acc[j] = a1 + a2;
        }
        // tanh + hi/lo pack; this wave produces exactly bh[kt=w]
        Frag nh_h, nh_l;
        #pragma unroll
        for(int j=0;j<2;j++){
            float h0 = fast_tanh(acc[j][0]);
            float h1 = fast_tanh(acc[j][1]);
            float h2 = fast_tanh(acc[j][2]);
            float h3 = fast_tanh(acc[j][3]);
            const int q0 = j*2;                 // jt = 2w+j -> (jt&1)=j
            uint32_t u0 = pk2(h0,h1), u1 = pk2(h2,h3);
            nh_h.u[q0]   = u0;
            nh_h.u[q0+1] = u1;
            nh_l.u[q0]   = pk2(h0-lo16f(u0), h1-hi16f(u0));
            nh_l.u[q0+1] = pk2(h2-lo16f(u1), h3-hi16f(u1));
        }
        // exchange via LDS (double-buffered, one barrier/step)
        const int buf = t & 1;
        *(u32x4*)(&lds[buf][0][w][lane][0]) = nh_h.v;
        *(u32x4*)(&lds[buf][1][w][lane][0]) = nh_l.v;
        __syncthreads();
        #pragma unroll
        for(int kt=0;kt<4;kt++){
            bh_h[kt].v = *(const u32x4*)(&lds[buf][0][kt][lane][0]);
            bh_l[kt].v = *(const u32x4*)(&lds[buf][1][kt][lane][0]);
        }
        xA = xA_n; xB = xB_n;
    }

    // ---- FC epilogue on wave 0 (it holds the full final h fragments) ----
    if (w == 0){
        Frag wfc_h[4], wfc_l[4];
        const bool valid = (c < 10);
        const float* rp = Wfc + (valid ? c : 0)*128;
        #pragma unroll
        for(int kt=0;kt<4;kt++){
            f32x4 a = *(const f32x4*)(rp + kt*32 + 8*g);
            f32x4 b = *(const f32x4*)(rp + kt*32 + 8*g + 4);
            if(!valid){ a = zero4; b = zero4; }
            cvt8(a, b, wfc_h[kt], wfc_l[kt]);
        }
        f32x4 accf = {0.f,0.f,0.f,0.f};
        #pragma unroll
        for(int kt=0;kt<4;kt++){
            accf = MFMA16(wfc_h[kt].s, bh_h[kt].s, accf);
            accf = MFMA16(wfc_l[kt].s, bh_h[kt].s, accf);
            accf = MFMA16(wfc_h[kt].s, bh_l[kt].s, accf);
        }
        #pragma unroll
        for(int r=0;r<4;r++){
            int cls = 4*g + r;
            if (cls < 10){
                out[(size_t)(b0+c)*10 + cls] = accf[r] + bfc[cls];
            }
        }
    }
}

extern "C" void kernel_launch(void* const* d_in, const int* in_sizes, int n_in,
                              void* d_out, int out_size, void* d_ws, size_t ws_size,
                              hipStream_t stream)
{
    const float* x   = (const float*)d_in[0];
    const float* Wih = (const float*)d_in[1];
    const float* Whh = (const float*)d_in[2];
    const float* bih = (const float*)d_in[3];
    const float* bhh = (const float*)d_in[4];
    const float* Wfc = (const float*)d_in[5];
    const float* bfc = (const float*)d_in[6];
    float* out = (float*)d_out;

    const int nb = in_sizes[0] / 784;      // 16384
    dim3 grid(nb/16), blk(256);
    hipLaunchKernelGGL(rnn_fused4, grid, blk, 0, stream,
                       x, Wih, Whh, bih, bhh, Wfc, bfc, out);
}

// Round 5
// 146.458 us; speedup vs baseline: 1.1173x; 1.0144x over previous
//
#include <hip/hip_runtime.h>
#include <hip/hip_bf16.h>
#include <stdint.h>

// SimpleRNN fused v3: B=16384, T=28, I=28, H=128, C=10, fp32 I/O.
// 1024 blocks x 2 waves; each wave owns 4 of 8 hidden-row tiles (jt=4w+j),
// 16 batch rows. h exchanged per step via double-buffered LDS with a raw
// s_barrier (lgkm-only drain -> x prefetch survives the barrier).
// bf16 hi/lo split MFMAs, fp32 accum. Hidden-unit permutation makes
// D-layout == next-step B-frag layout (zero data movement per step).

typedef __attribute__((ext_vector_type(8))) short short8;
typedef __attribute__((ext_vector_type(4))) float f32x4;
typedef __attribute__((ext_vector_type(4))) uint32_t u32x4;

union Frag { short8 s; uint32_t u[4]; u32x4 v; };

#define MFMA16(a,b,c) __builtin_amdgcn_mfma_f32_16x16x32_bf16((a),(b),(c),0,0,0)

__device__ __forceinline__ uint32_t pk2(float a, float b){
    union { __hip_bfloat162 h; uint32_t u; } cv;
    cv.h = __float22bfloat162_rn(make_float2(a,b));
    return cv.u;
}
__device__ __forceinline__ float lo16f(uint32_t u){ return __builtin_bit_cast(float, u<<16); }
__device__ __forceinline__ float hi16f(uint32_t u){ return __builtin_bit_cast(float, u & 0xffff0000u); }

__device__ __forceinline__ void cvt8(const f32x4& a, const f32x4& b, Frag& hi, Frag& lo){
    #pragma unroll
    for(int q=0;q<2;q++){
        uint32_t h = pk2(a[2*q], a[2*q+1]);
        hi.u[q] = h;
        lo.u[q] = pk2(a[2*q]-lo16f(h), a[2*q+1]-hi16f(h));
    }
    #pragma unroll
    for(int q=0;q<2;q++){
        uint32_t h = pk2(b[2*q], b[2*q+1]);
        hi.u[2+q] = h;
        lo.u[2+q] = pk2(b[2*q]-lo16f(h), b[2*q+1]-hi16f(h));
    }
}

// D slot (jt, rowidx) -> physical hidden index (layout fixed point)
__device__ __forceinline__ int piperm(int p){
    int jt = p>>4, c = p&15;
    return 32*(jt>>1) + 8*(c>>2) + 4*(jt&1) + (c&3);
}

// clamp-free tanh: 1 - 2/(e^{2x}+1). e->inf => 1, e->0 => -1. 5 VALU ops.
__device__ __forceinline__ float fast_tanh(float x){
    float e = __expf(2.f*x);
    return 1.f - 2.f*__builtin_amdgcn_rcpf(e + 1.f);
}

__global__ __launch_bounds__(128,2) void rnn_v3(
    const float* __restrict__ x,   const float* __restrict__ Wih,
    const float* __restrict__ Whh, const float* __restrict__ bih,
    const float* __restrict__ bhh, const float* __restrict__ Wfc,
    const float* __restrict__ bfc, float* __restrict__ out)
{
    const int tid  = threadIdx.x;
    const int w    = tid >> 6;        // wave 0..1, owns jt = 4w+j (j=0..3)
    const int lane = tid & 63;
    const int g = lane>>4, c = lane&15;
    const int b0 = blockIdx.x*16;
    const f32x4 zero4 = {0.f,0.f,0.f,0.f};

    // h exchange: [buf][hi/lo][kt][lane][4 u32] = 16 KB, double-buffered
    __shared__ uint32_t lds[2][2][4][64][4];

    // ---- W_hh fragments for this wave's 4 jt tiles (rows pi-permuted) ----
    Frag whh_h[4][4], whh_l[4][4];
    #pragma unroll
    for(int j=0;j<4;j++){
        const int row = piperm(16*(4*w+j) + c);
        const float* rp = Whh + row*128;
        #pragma unroll
        for(int kt=0;kt<4;kt++){
            f32x4 a = *(const f32x4*)(rp + kt*32 + 8*g);
            f32x4 b = *(const f32x4*)(rp + kt*32 + 8*g + 4);
            cvt8(a, b, whh_h[j][kt], whh_l[j][kt]);
        }
    }

    // ---- W_ih fragments (K=28 padded to 32; pad slots zeroed HERE so the
    //      per-step x fragment needs no masking: garbage * 0 == 0) ----
    Frag wih_h[4], wih_l[4];
    {
        const int i1 = 8*g;
        const int i2 = (g<3) ? (8*g+4) : 24;
        #pragma unroll
        for(int j=0;j<4;j++){
            const int row = piperm(16*(4*w+j) + c);
            const float* rp = Wih + row*28;
            f32x4 a = *(const f32x4*)(rp + i1);
            f32x4 b = *(const f32x4*)(rp + i2);
            if (g==3) b = zero4;              // zero weights for k=28..31
            cvt8(a, b, wih_h[j], wih_l[j]);
        }
    }

    // ---- biases as MFMA C-operand ----
    f32x4 biasr[4];
    #pragma unroll
    for(int j=0;j<4;j++){
        #pragma unroll
        for(int r=0;r<4;r++){
            int q = piperm(16*(4*w+j) + 4*g + r);
            biasr[j][r] = bih[q] + bhh[q];
        }
    }

    // ---- h state fragments (full 128-wide B-layout), zero init ----
    Frag bh_h[4], bh_l[4];
    #pragma unroll
    for(int kt=0;kt<4;kt++){
        #pragma unroll
        for(int q=0;q<4;q++){ bh_h[kt].u[q]=0; bh_l[kt].u[q]=0; }
    }

    const float* xrow = x + (size_t)(b0 + c)*784;
    const int o1 = 8*g;
    const int o2 = (g<3) ? (8*g+4) : 24;      // g==3 reads dup of 24..27 (x0 weight)

    f32x4 xA = *(const f32x4*)(xrow + o1);
    f32x4 xB = *(const f32x4*)(xrow + o2);

    for(int t=0; t<28; ++t){
        // prefetch next timestep's x (survives the raw barrier: no vmcnt drain)
        const int tn = (t<27) ? t+1 : 27;
        f32x4 xA_n = *(const f32x4*)(xrow + tn*28 + o1);
        f32x4 xB_n = *(const f32x4*)(xrow + tn*28 + o2);

        // x -> B fragment (no masking needed; pad weights are zero)
        Frag bx_h, bx_l;
        cvt8(xA, xB, bx_h, bx_l);

        // preact = bias + W_ih x_t + W_hh h ; 8 parallel MFMA chains
        f32x4 acc[4];
        #pragma unroll
        for(int j=0;j<4;j++){
            f32x4 a1 = MFMA16(wih_h[j].s, bx_h.s, biasr[j]);
            a1 = MFMA16(wih_l[j].s, bx_h.s, a1);
            a1 = MFMA16(wih_h[j].s, bx_l.s, a1);
            a1 = MFMA16(whh_h[j][0].s, bh_h[0].s, a1);
            a1 = MFMA16(whh_l[j][0].s, bh_h[0].s, a1);
            a1 = MFMA16(whh_h[j][0].s, bh_l[0].s, a1);
            a1 = MFMA16(whh_h[j][1].s, bh_h[1].s, a1);
            a1 = MFMA16(whh_l[j][1].s, bh_h[1].s, a1);
            a1 = MFMA16(whh_h[j][1].s, bh_l[1].s, a1);
            f32x4 a2 = MFMA16(whh_h[j][2].s, bh_h[2].s, zero4);
            a2 = MFMA16(whh_l[j][2].s, bh_h[2].s, a2);
            a2 = MFMA16(whh_h[j][2].s, bh_l[2].s, a2);
            a2 = MFMA16(whh_h[j][3].s, bh_h[3].s, a2);
            a2 = MFMA16(whh_l[j][3].s, bh_h[3].s, a2);
            a2 = MFMA16(whh_h[j][3].s, bh_l[3].s, a2);
            acc[j] = a1 + a2;
        }

        // tanh + hi/lo pack; wave w produces kt slices {2w, 2w+1}
        Frag nh_h[2], nh_l[2];
        #pragma unroll
        for(int j=0;j<4;j++){
            float h0 = fast_tanh(acc[j][0]);
            float h1 = fast_tanh(acc[j][1]);
            float h2 = fast_tanh(acc[j][2]);
            float h3 = fast_tanh(acc[j][3]);
            const int sl = j>>1;                // local kt slice
            const int q0 = (j&1)*2;
            uint32_t u0 = pk2(h0,h1), u1 = pk2(h2,h3);
            nh_h[sl].u[q0]   = u0;
            nh_h[sl].u[q0+1] = u1;
            nh_l[sl].u[q0]   = pk2(h0-lo16f(u0), h1-hi16f(u0));
            nh_l[sl].u[q0+1] = pk2(h2-lo16f(u1), h3-hi16f(u1));
        }

        // exchange via LDS; raw barrier drains LDS only (x loads stay in flight)
        const int buf = t & 1;
        *(u32x4*)(&lds[buf][0][2*w  ][lane][0]) = nh_h[0].v;
        *(u32x4*)(&lds[buf][1][2*w  ][lane][0]) = nh_l[0].v;
        *(u32x4*)(&lds[buf][0][2*w+1][lane][0]) = nh_h[1].v;
        *(u32x4*)(&lds[buf][1][2*w+1][lane][0]) = nh_l[1].v;

        asm volatile("s_waitcnt lgkmcnt(0)" ::: "memory");
        __builtin_amdgcn_s_barrier();

        #pragma unroll
        for(int kt=0;kt<4;kt++){
            bh_h[kt].v = *(const u32x4*)(&lds[buf][0][kt][lane][0]);
            bh_l[kt].v = *(const u32x4*)(&lds[buf][1][kt][lane][0]);
        }
        xA = xA_n; xB = xB_n;
    }

    // ---- FC epilogue on wave 0 (holds full final h fragments) ----
    if (w == 0){
        Frag wfc_h[4], wfc_l[4];
        const bool valid = (c < 10);
        const float* rp = Wfc + (valid ? c : 0)*128;
        #pragma unroll
        for(int kt=0;kt<4;kt++){
            f32x4 a = *(const f32x4*)(rp + kt*32 + 8*g);
            f32x4 b = *(const f32x4*)(rp + kt*32 + 8*g + 4);
            if(!valid){ a = zero4; b = zero4; }
            cvt8(a, b, wfc_h[kt], wfc_l[kt]);
        }
        f32x4 accf = {0.f,0.f,0.f,0.f};
        #pragma unroll
        for(int kt=0;kt<4;kt++){
            accf = MFMA16(wfc_h[kt].s, bh_h[kt].s, accf);
            accf = MFMA16(wfc_l[kt].s, bh_h[kt].s, accf);
            accf = MFMA16(wfc_h[kt].s, bh_l[kt].s, accf);
        }
        #pragma unroll
        for(int r=0;r<4;r++){
            int cls = 4*g + r;
            if (cls < 10){
                out[(size_t)(b0+c)*10 + cls] = accf[r] + bfc[cls];
            }
        }
    }
}

extern "C" void kernel_launch(void* const* d_in, const int* in_sizes, int n_in,
                              void* d_out, int out_size, void* d_ws, size_t ws_size,
                              hipStream_t stream)
{
    const float* x   = (const float*)d_in[0];
    const float* Wih = (const float*)d_in[1];
    const float* Whh = (const float*)d_in[2];
    const float* bih = (const float*)d_in[3];
    const float* bhh = (const float*)d_in[4];
    const float* Wfc = (const float*)d_in[5];
    const float* bfc = (const float*)d_in[6];
    float* out = (float*)d_out;

    const int nb = in_sizes[0] / 784;      // 16384
    dim3 grid(nb/16), blk(128);
    hipLaunchKernelGGL(rnn_v3, grid, blk, 0, stream,
                       x, Wih, Whh, bih, bhh, Wfc, bfc, out);
}